// Round 1
// baseline (2746.687 us; speedup 1.0000x reference)
//
#include <hip/hip_runtime.h>
#include <hip/hip_bf16.h>
#include <math.h>

// Problem constants (B=1, H=W=192)
#define IMG_H 192
#define IMG_W 192
#define NPIX (IMG_H * IMG_W)   // 36864

// ---------------------------------------------------------------------------
// Generic 3x3 SAME conv, direct / implicit-GEMM style.
// Block: 256 threads = 16x16 spatial tile; each thread computes 16 output
// channels (grid.y selects the channel group). Input staged via LDS in
// 8-channel chunks; weights read with wave-uniform indices (-> s_load).
// ACT: 0 = none, 1 = leaky-relu(0.1), 2 = deform-head activation
//      (c<288 -> 5*tanh, else sigmoid).
// ---------------------------------------------------------------------------
template<int CIN, int ACT>
__global__ __launch_bounds__(256) void conv3x3_k(
    const float* __restrict__ in, const float* __restrict__ wgt,
    const float* __restrict__ bias, float* __restrict__ out)
{
    constexpr int CHUNK = 8;                 // input channels per LDS stage
    __shared__ float tile[CHUNK][18 * 18];   // 18x18 halo tile per channel

    const int t  = threadIdx.x;
    const int tx = t & 15;
    const int ty = t >> 4;
    const int tile_id = blockIdx.x;          // 0..143 (12x12 tiles of 16x16)
    const int tx0 = (tile_id % 12) * 16;
    const int ty0 = (tile_id / 12) * 16;
    const int cobase = blockIdx.y * 16;
    const int gx = tx0 + tx;
    const int gy = ty0 + ty;

    float acc[16];
#pragma unroll
    for (int i = 0; i < 16; i++) acc[i] = 0.f;

    for (int c0 = 0; c0 < CIN; c0 += CHUNK) {
        __syncthreads();
        // cooperative load: CHUNK channels of an 18x18 halo tile (zero-pad)
        for (int idx = t; idx < CHUNK * 324; idx += 256) {
            const int cl  = idx / 324;
            const int rem = idx - cl * 324;
            const int r   = rem / 18;
            const int cc  = rem - r * 18;
            const int sy = ty0 + r - 1;
            const int sx = tx0 + cc - 1;
            float v = 0.f;
            if (sy >= 0 && sy < IMG_H && sx >= 0 && sx < IMG_W)
                v = in[(c0 + cl) * NPIX + sy * IMG_W + sx];
            tile[cl][rem] = v;
        }
        __syncthreads();

#pragma unroll
        for (int cl = 0; cl < CHUNK; cl++) {
            float v[9];
#pragma unroll
            for (int ky = 0; ky < 3; ky++)
#pragma unroll
                for (int kx = 0; kx < 3; kx++)
                    v[ky * 3 + kx] = tile[cl][(ty + ky) * 18 + (tx + kx)];
#pragma unroll
            for (int co = 0; co < 16; co++) {
                const float* wp = wgt + ((size_t)(cobase + co) * CIN + (c0 + cl)) * 9;
#pragma unroll
                for (int k = 0; k < 9; k++)
                    acc[co] = fmaf(wp[k], v[k], acc[co]);
            }
        }
    }

#pragma unroll
    for (int co = 0; co < 16; co++) {
        const int c = cobase + co;
        float r = acc[co] + bias[c];
        if (ACT == 1) {
            r = (r >= 0.f) ? r : 0.1f * r;
        } else if (ACT == 2) {
            if (c < 288) r = 5.f * tanhf(r);
            else         r = 1.f / (1.f + __expf(-r));
        }
        out[(size_t)c * NPIX + gy * IMG_W + gx] = r;
    }
}

// ---------------------------------------------------------------------------
// Deformable conv: x (128,H,W), activated offsets/mask od (432,H,W),
// weight (64,128,3,3), bias (64) -> out (64,H,W).  DG=16 groups of Cg=8.
// Block: 256 threads = 4 waves over one 8x8 pixel tile. Each wave samples
// 2 of the 8 group-channels (shared via LDS) and owns 16 output channels
// for the einsum. 576 blocks total.
// ---------------------------------------------------------------------------
__global__ __launch_bounds__(256) void deform_k(
    const float* __restrict__ x, const float* __restrict__ od,
    const float* __restrict__ wgt, const float* __restrict__ bias,
    float* __restrict__ out)
{
    __shared__ float smem[8 * 9 * 64];   // [ch_local][k][pixel]

    const int t   = threadIdx.x;
    const int p   = t & 63;                                  // pixel in 8x8 tile
    const int sub = __builtin_amdgcn_readfirstlane(t >> 6);  // wave id 0..3
    const int tile = blockIdx.x;                             // 0..575 (24x24 tiles)
    const int tx0 = (tile % 24) * 8;
    const int ty0 = (tile / 24) * 8;
    const int lx = p & 7;
    const int ly = p >> 3;
    const int gx = tx0 + lx;
    const int gy = ty0 + ly;
    const int pix = gy * IMG_W + gx;
    const int cobase = sub * 16;

    float acc[16];
#pragma unroll
    for (int i = 0; i < 16; i++) acc[i] = 0.f;

    for (int dg = 0; dg < 16; dg++) {
        __syncthreads();   // previous iteration's smem reads done
#pragma unroll
        for (int k = 0; k < 9; k++) {
            const int kc = dg * 9 + k;
            const float oy = od[(size_t)(kc * 2 + 0) * NPIX + pix];
            const float ox = od[(size_t)(kc * 2 + 1) * NPIX + pix];
            const float m  = od[(size_t)(288 + kc)   * NPIX + pix];
            const float py = (float)(gy - 1 + k / 3) + oy;
            const float px = (float)(gx - 1 + k % 3) + ox;
            const float y0f = floorf(py);
            const float x0f = floorf(px);
            const float wy1 = py - y0f, wx1 = px - x0f;
            const float wy0 = 1.f - wy1, wx0 = 1.f - wx1;
            const int iy0 = (int)y0f, ix0 = (int)x0f;
            const int iy1 = iy0 + 1,  ix1 = ix0 + 1;
            const float vy0 = (iy0 >= 0 && iy0 < IMG_H) ? 1.f : 0.f;
            const float vy1 = (iy1 >= 0 && iy1 < IMG_H) ? 1.f : 0.f;
            const float vx0 = (ix0 >= 0 && ix0 < IMG_W) ? 1.f : 0.f;
            const float vx1 = (ix1 >= 0 && ix1 < IMG_W) ? 1.f : 0.f;
            const int cy0 = min(max(iy0, 0), IMG_H - 1);
            const int cy1 = min(max(iy1, 0), IMG_H - 1);
            const int cx0 = min(max(ix0, 0), IMG_W - 1);
            const int cx1 = min(max(ix1, 0), IMG_W - 1);
            const float w00 = wy0 * wx0 * m * vy0 * vx0;
            const float w01 = wy0 * wx1 * m * vy0 * vx1;
            const float w10 = wy1 * wx0 * m * vy1 * vx0;
            const float w11 = wy1 * wx1 * m * vy1 * vx1;
            const int i00 = cy0 * IMG_W + cx0;
            const int i01 = cy0 * IMG_W + cx1;
            const int i10 = cy1 * IMG_W + cx0;
            const int i11 = cy1 * IMG_W + cx1;
#pragma unroll
            for (int cc = 0; cc < 2; cc++) {
                const int chl = sub * 2 + cc;          // 0..7 within group
                const float* xp = x + (size_t)(dg * 8 + chl) * NPIX;
                const float v = w00 * xp[i00] + w01 * xp[i01]
                              + w10 * xp[i10] + w11 * xp[i11];
                smem[chl * 576 + k * 64 + p] = v;
            }
        }
        __syncthreads();

#pragma unroll
        for (int cg = 0; cg < 8; cg++) {
            float v[9];
#pragma unroll
            for (int k = 0; k < 9; k++) v[k] = smem[cg * 576 + k * 64 + p];
            const int c = dg * 8 + cg;
#pragma unroll
            for (int co = 0; co < 16; co++) {
                const float* wp = wgt + ((size_t)(cobase + co) * 128 + c) * 9;
#pragma unroll
                for (int k = 0; k < 9; k++)
                    acc[co] = fmaf(wp[k], v[k], acc[co]);
            }
        }
    }

#pragma unroll
    for (int co = 0; co < 16; co++) {
        const int c = cobase + co;
        out[(size_t)c * NPIX + pix] = acc[co] + bias[c];
    }
}

// ---------------------------------------------------------------------------
// Launch
// ---------------------------------------------------------------------------
extern "C" void kernel_launch(void* const* d_in, const int* in_sizes, int n_in,
                              void* d_out, int out_size, void* d_ws, size_t ws_size,
                              hipStream_t stream) {
    (void)in_sizes; (void)n_in; (void)out_size; (void)ws_size;

    const float* x      = (const float*)d_in[0];   // (1,128,192,192)
    const float* cond   = (const float*)d_in[1];   // (1,192,192,192)
    const float* weight = (const float*)d_in[2];   // (64,128,3,3)
    const float* bias   = (const float*)d_in[3];   // (64,)
    const float* w1     = (const float*)d_in[4];   // (64,192,3,3)
    const float* b1     = (const float*)d_in[5];
    const float* w2     = (const float*)d_in[6];   // (64,64,3,3)
    const float* b2     = (const float*)d_in[7];
    const float* w3     = (const float*)d_in[8];   // (64,64,3,3)
    const float* b3     = (const float*)d_in[9];
    const float* w4     = (const float*)d_in[10];  // (432,64,3,3)
    const float* b4     = (const float*)d_in[11];
    float* out = (float*)d_out;                    // (1,64,192,192)

    float* h1 = (float*)d_ws;                      // 64*NPIX
    float* h2 = h1 + (size_t)64 * NPIX;            // 64*NPIX
    float* o4 = h2 + (size_t)64 * NPIX;            // 432*NPIX (activated head)

    const dim3 blk(256);
    hipLaunchKernelGGL((conv3x3_k<192, 1>), dim3(144, 4),  blk, 0, stream, cond, w1, b1, h1);
    hipLaunchKernelGGL((conv3x3_k<64, 1>),  dim3(144, 4),  blk, 0, stream, h1,   w2, b2, h2);
    hipLaunchKernelGGL((conv3x3_k<64, 1>),  dim3(144, 4),  blk, 0, stream, h2,   w3, b3, h1);
    hipLaunchKernelGGL((conv3x3_k<64, 2>),  dim3(144, 27), blk, 0, stream, h1,   w4, b4, o4);
    hipLaunchKernelGGL(deform_k,            dim3(576),     blk, 0, stream, x, o4, weight, bias, out);
}

// Round 2
// 847.568 us; speedup vs baseline: 3.2407x; 3.2407x over previous
//
#include <hip/hip_runtime.h>
#include <hip/hip_bf16.h>
#include <math.h>

#define IMG_H 192
#define IMG_W 192
#define NPIX (IMG_H * IMG_W)      // 36864
#define PADW 194
#define PPIX (PADW * PADW)        // 37636

typedef _Float16 h8 __attribute__((ext_vector_type(8)));
typedef float f32x4 __attribute__((ext_vector_type(4)));

// ---------------------------------------------------------------------------
// Prep: fp32 [C][192][192] -> fp16 zero-padded [C][194][194]
// ---------------------------------------------------------------------------
__global__ __launch_bounds__(256) void pad_to_half_k(
    const float* __restrict__ src, _Float16* __restrict__ dst)
{
    const int y  = blockIdx.x;   // 0..193
    const int ch = blockIdx.y;
    const int x  = threadIdx.x;
    if (x >= PADW) return;
    _Float16 v = (_Float16)0.f;
    if (y >= 1 && y <= IMG_H && x >= 1 && x <= IMG_W)
        v = (_Float16)src[(size_t)ch * NPIX + (y - 1) * IMG_W + (x - 1)];
    dst[(size_t)ch * PPIX + y * PADW + x] = v;
}

// ---------------------------------------------------------------------------
// Prep: pack fp32 weights [co][CIN][3][3] -> fp16 [chunk][k][co<COP][ci32]
// grid.x = (CIN/32)*9 ; co >= COUT zero-filled.
// ---------------------------------------------------------------------------
template<int CIN, int COP, int COUT>
__global__ __launch_bounds__(256) void pack_w_k(
    const float* __restrict__ src, _Float16* __restrict__ dst)
{
    const int bx = blockIdx.x;          // chunk*9 + k
    const int chunk = bx / 9, k = bx % 9;
    for (int i = threadIdx.x; i < COP * 32; i += 256) {
        const int co = i >> 5, cil = i & 31;
        float v = 0.f;
        if (co < COUT)
            v = src[((size_t)(co * CIN + chunk * 32 + cil)) * 9 + k];
        dst[(size_t)bx * COP * 32 + i] = (_Float16)v;
    }
}

// ---------------------------------------------------------------------------
// MFMA conv3x3. Block: 256 thr = 4 waves; 16x16 pixel tile; 64 out channels.
// Each wave: 64(co) x 64(px) MFMA tile = 4 A-frags x 4 B-frags x 16 mfma /k.
// LDS strides are 32 fp16 (64 B) -> b128 accesses hit every bank exactly
// 8x (= the 1024B/128B-per-cyc floor): conflict-free by construction.
// ACT 1: lrelu -> padded fp16 out. ACT 2: deform head (5*tanh / sigmoid)
// -> fp16 planar od[432][NPIX].
// ---------------------------------------------------------------------------
template<int CHUNKS, int ACT, int COP>
__global__ __launch_bounds__(256) void conv_mfma_k(
    const _Float16* __restrict__ in_pad,   // [CIN][PPIX]
    const _Float16* __restrict__ wpk,      // [CHUNKS][9][COP][32]
    const float* __restrict__ bias,
    _Float16* __restrict__ out)
{
    __shared__ _Float16 in_lds[324 * 32];  // [pix 18x18][ci 32]
    __shared__ _Float16 w_lds[9 * 64 * 32];// [k][co 64][ci 32]

    const int t    = threadIdx.x;
    const int lane = t & 63;
    const int wv   = __builtin_amdgcn_readfirstlane(t >> 6);
    const int col  = lane & 15;
    const int quad = lane >> 4;
    const int bx   = blockIdx.x;
    const int tx0  = (bx % 12) * 16;
    const int ty0  = (bx / 12) * 16;
    const int cobase = blockIdx.y * 64;

    f32x4 acc[4][4];
#pragma unroll
    for (int m = 0; m < 4; m++)
#pragma unroll
        for (int s = 0; s < 4; s++) {
            f32x4 z = {0.f, 0.f, 0.f, 0.f};
            acc[m][s] = z;
        }

    for (int c = 0; c < CHUNKS; c++) {
        __syncthreads();
        // ---- stage input: 18 halo rows x 16 channel-pairs = 288 jobs ----
        for (int p = t; p < 288; p += 256) {
            const int row = p >> 4;       // 0..17
            const int ci2 = p & 15;       // channel pair
            const size_t gbase = ((size_t)(c * 32 + 2 * ci2)) * PPIX
                               + (size_t)(ty0 + row) * PADW + tx0;
            const unsigned int* gA = (const unsigned int*)(in_pad + gbase);
            const unsigned int* gB = (const unsigned int*)(in_pad + gbase + PPIX);
            unsigned int* dst = (unsigned int*)in_lds;  // word idx = pix*16 + ci2
#pragma unroll
            for (int j = 0; j < 9; j++) {
                const unsigned int a = gA[j], b = gB[j];
                const int pix = row * 18 + 2 * j;
                dst[pix * 16 + ci2]       = (a & 0xffffu) | (b << 16);
                dst[(pix + 1) * 16 + ci2] = (a >> 16) | (b & 0xffff0000u);
            }
        }
        // ---- stage weights: 9 k x 64 co = 576 rows of 32 fp16 (64 B) ----
        for (int p = t; p < 576; p += 256) {
            const int k = p >> 6, co = p & 63;
            const uint4* s4 = (const uint4*)(wpk
                + (((size_t)c * 9 + k) * COP + cobase + co) * 32);
            uint4* dl = (uint4*)&w_lds[(k * 64 + co) * 32];
            dl[0] = s4[0]; dl[1] = s4[1]; dl[2] = s4[2]; dl[3] = s4[3];
        }
        __syncthreads();

#pragma unroll
        for (int k = 0; k < 9; k++) {
            const int ky = k / 3, kx = k % 3;
            h8 af[4], bf[4];
#pragma unroll
            for (int m = 0; m < 4; m++)
                af[m] = *(const h8*)&w_lds[(k * 64 + m * 16 + col) * 32 + quad * 8];
#pragma unroll
            for (int s = 0; s < 4; s++)
                bf[s] = *(const h8*)&in_lds[((4 * wv + s + ky) * 18 + col + kx) * 32 + quad * 8];
#pragma unroll
            for (int m = 0; m < 4; m++)
#pragma unroll
                for (int s = 0; s < 4; s++)
                    acc[m][s] = __builtin_amdgcn_mfma_f32_16x16x32_f16(
                        af[m], bf[s], acc[m][s], 0, 0, 0);
        }
    }

    // ---- epilogue: D row = co (quad*4+r), D col = pixel col (lane&15) ----
#pragma unroll
    for (int m = 0; m < 4; m++) {
#pragma unroll
        for (int s = 0; s < 4; s++) {
            const int gy = ty0 + 4 * wv + s;
            const int gx = tx0 + col;
#pragma unroll
            for (int r = 0; r < 4; r++) {
                const int co = cobase + m * 16 + quad * 4 + r;
                float v = acc[m][s][r];
                if (ACT == 1) {
                    v += bias[co];
                    v = (v >= 0.f) ? v : 0.1f * v;
                    out[(size_t)co * PPIX + (gy + 1) * PADW + (gx + 1)] = (_Float16)v;
                } else {
                    if (co < 432) {
                        v += bias[co];
                        if (co < 288) v = 5.f * tanhf(v);
                        else          v = 1.f / (1.f + __expf(-v));
                        out[(size_t)co * NPIX + gy * IMG_W + gx] = (_Float16)v;
                    }
                }
            }
        }
    }
}

// ---------------------------------------------------------------------------
// Deformable conv (unchanged from R1 except od is fp16 now).
// ---------------------------------------------------------------------------
__global__ __launch_bounds__(256) void deform_k(
    const float* __restrict__ x, const _Float16* __restrict__ od,
    const float* __restrict__ wgt, const float* __restrict__ bias,
    float* __restrict__ out)
{
    __shared__ float smem[8 * 9 * 64];   // [ch_local][k][pixel]

    const int t   = threadIdx.x;
    const int p   = t & 63;
    const int sub = __builtin_amdgcn_readfirstlane(t >> 6);
    const int tile = blockIdx.x;                       // 0..575 (24x24 tiles)
    const int tx0 = (tile % 24) * 8;
    const int ty0 = (tile / 24) * 8;
    const int lx = p & 7;
    const int ly = p >> 3;
    const int gx = tx0 + lx;
    const int gy = ty0 + ly;
    const int pix = gy * IMG_W + gx;
    const int cobase = sub * 16;

    float acc[16];
#pragma unroll
    for (int i = 0; i < 16; i++) acc[i] = 0.f;

    for (int dg = 0; dg < 16; dg++) {
        __syncthreads();
#pragma unroll
        for (int k = 0; k < 9; k++) {
            const int kc = dg * 9 + k;
            const float oy = (float)od[(size_t)(kc * 2 + 0) * NPIX + pix];
            const float ox = (float)od[(size_t)(kc * 2 + 1) * NPIX + pix];
            const float m  = (float)od[(size_t)(288 + kc)   * NPIX + pix];
            const float py = (float)(gy - 1 + k / 3) + oy;
            const float px = (float)(gx - 1 + k % 3) + ox;
            const float y0f = floorf(py);
            const float x0f = floorf(px);
            const float wy1 = py - y0f, wx1 = px - x0f;
            const float wy0 = 1.f - wy1, wx0 = 1.f - wx1;
            const int iy0 = (int)y0f, ix0 = (int)x0f;
            const int iy1 = iy0 + 1,  ix1 = ix0 + 1;
            const float vy0 = (iy0 >= 0 && iy0 < IMG_H) ? 1.f : 0.f;
            const float vy1 = (iy1 >= 0 && iy1 < IMG_H) ? 1.f : 0.f;
            const float vx0 = (ix0 >= 0 && ix0 < IMG_W) ? 1.f : 0.f;
            const float vx1 = (ix1 >= 0 && ix1 < IMG_W) ? 1.f : 0.f;
            const int cy0 = min(max(iy0, 0), IMG_H - 1);
            const int cy1 = min(max(iy1, 0), IMG_H - 1);
            const int cx0 = min(max(ix0, 0), IMG_W - 1);
            const int cx1 = min(max(ix1, 0), IMG_W - 1);
            const float w00 = wy0 * wx0 * m * vy0 * vx0;
            const float w01 = wy0 * wx1 * m * vy0 * vx1;
            const float w10 = wy1 * wx0 * m * vy1 * vx0;
            const float w11 = wy1 * wx1 * m * vy1 * vx1;
            const int i00 = cy0 * IMG_W + cx0;
            const int i01 = cy0 * IMG_W + cx1;
            const int i10 = cy1 * IMG_W + cx0;
            const int i11 = cy1 * IMG_W + cx1;
#pragma unroll
            for (int cc = 0; cc < 2; cc++) {
                const int chl = sub * 2 + cc;
                const float* xp = x + (size_t)(dg * 8 + chl) * NPIX;
                const float v = w00 * xp[i00] + w01 * xp[i01]
                              + w10 * xp[i10] + w11 * xp[i11];
                smem[chl * 576 + k * 64 + p] = v;
            }
        }
        __syncthreads();

#pragma unroll
        for (int cg = 0; cg < 8; cg++) {
            float v[9];
#pragma unroll
            for (int k = 0; k < 9; k++) v[k] = smem[cg * 576 + k * 64 + p];
            const int c = dg * 8 + cg;
#pragma unroll
            for (int co = 0; co < 16; co++) {
                const float* wp = wgt + ((size_t)(cobase + co) * 128 + c) * 9;
#pragma unroll
                for (int k = 0; k < 9; k++)
                    acc[co] = fmaf(wp[k], v[k], acc[co]);
            }
        }
    }

#pragma unroll
    for (int co = 0; co < 16; co++) {
        const int c = cobase + co;
        out[(size_t)c * NPIX + pix] = acc[co] + bias[c];
    }
}

// ---------------------------------------------------------------------------
// Launch
// ---------------------------------------------------------------------------
extern "C" void kernel_launch(void* const* d_in, const int* in_sizes, int n_in,
                              void* d_out, int out_size, void* d_ws, size_t ws_size,
                              hipStream_t stream) {
    (void)in_sizes; (void)n_in; (void)out_size; (void)ws_size;

    const float* x      = (const float*)d_in[0];
    const float* cond   = (const float*)d_in[1];
    const float* weight = (const float*)d_in[2];
    const float* bias   = (const float*)d_in[3];
    const float* w1     = (const float*)d_in[4];
    const float* b1     = (const float*)d_in[5];
    const float* w2     = (const float*)d_in[6];
    const float* b2     = (const float*)d_in[7];
    const float* w3     = (const float*)d_in[8];
    const float* b3     = (const float*)d_in[9];
    const float* w4     = (const float*)d_in[10];
    const float* b4     = (const float*)d_in[11];
    float* out = (float*)d_out;

    char* ws = (char*)d_ws;
    size_t off = 0;
    auto take = [&](size_t bytes) -> char* {
        char* p = ws + off;
        off = (off + bytes + 255) & ~(size_t)255;
        return p;
    };
    _Float16* pad_cond = (_Float16*)take((size_t)192 * PPIX * 2);
    _Float16* pb1      = (_Float16*)take((size_t)3 * 64 * PPIX * 2);
    _Float16* pb2 = pb1 + (size_t)64 * PPIX;
    _Float16* pb3 = pb2 + (size_t)64 * PPIX;
    _Float16* od  = (_Float16*)take((size_t)432 * NPIX * 2);
    _Float16* wp1 = (_Float16*)take((size_t)54 * 64 * 32 * 2);
    _Float16* wp2 = (_Float16*)take((size_t)18 * 64 * 32 * 2);
    _Float16* wp3 = (_Float16*)take((size_t)18 * 64 * 32 * 2);
    _Float16* wp4 = (_Float16*)take((size_t)18 * 448 * 32 * 2);

    hipMemsetAsync(pb1, 0, (size_t)3 * 64 * PPIX * 2, stream);
    hipLaunchKernelGGL(pad_to_half_k, dim3(PADW, 192), dim3(256), 0, stream, cond, pad_cond);
    hipLaunchKernelGGL((pack_w_k<192, 64, 64>),  dim3(54), dim3(256), 0, stream, w1, wp1);
    hipLaunchKernelGGL((pack_w_k<64, 64, 64>),   dim3(18), dim3(256), 0, stream, w2, wp2);
    hipLaunchKernelGGL((pack_w_k<64, 64, 64>),   dim3(18), dim3(256), 0, stream, w3, wp3);
    hipLaunchKernelGGL((pack_w_k<64, 448, 432>), dim3(18), dim3(256), 0, stream, w4, wp4);

    hipLaunchKernelGGL((conv_mfma_k<6, 1, 64>),  dim3(144, 1), dim3(256), 0, stream, pad_cond, wp1, b1, pb1);
    hipLaunchKernelGGL((conv_mfma_k<2, 1, 64>),  dim3(144, 1), dim3(256), 0, stream, pb1, wp2, b2, pb2);
    hipLaunchKernelGGL((conv_mfma_k<2, 1, 64>),  dim3(144, 1), dim3(256), 0, stream, pb2, wp3, b3, pb3);
    hipLaunchKernelGGL((conv_mfma_k<2, 2, 448>), dim3(144, 7), dim3(256), 0, stream, pb3, wp4, b4, od);
    hipLaunchKernelGGL(deform_k, dim3(576), dim3(256), 0, stream, x, od, weight, bias, out);
}

// Round 3
// 324.627 us; speedup vs baseline: 8.4611x; 2.6109x over previous
//
#include <hip/hip_runtime.h>
#include <hip/hip_bf16.h>
#include <math.h>

#define IMG_H 192
#define IMG_W 192
#define NPIX (IMG_H * IMG_W)      // 36864
#define PADW 194
#define PPIX (PADW * PADW)        // 37636
#define PH 208                    // deform-sample padded plane (offset +6)
#define PW 208

typedef _Float16 h8 __attribute__((ext_vector_type(8)));
typedef float f32x4 __attribute__((ext_vector_type(4)));

// ---------------------------------------------------------------------------
// Prep: fp32 [C][192][192] -> fp16 zero-padded [C][194][194]
// ---------------------------------------------------------------------------
__global__ __launch_bounds__(256) void pad_to_half_k(
    const float* __restrict__ src, _Float16* __restrict__ dst)
{
    const int y  = blockIdx.x;   // 0..193
    const int ch = blockIdx.y;
    const int x  = threadIdx.x;
    if (x >= PADW) return;
    _Float16 v = (_Float16)0.f;
    if (y >= 1 && y <= IMG_H && x >= 1 && x <= IMG_W)
        v = (_Float16)src[(size_t)ch * NPIX + (y - 1) * IMG_W + (x - 1)];
    dst[(size_t)ch * PPIX + y * PADW + x] = v;
}

// ---------------------------------------------------------------------------
// Prep: pack fp32 weights [co][CIN][3][3] -> fp16 [chunk][k][co<COP][ci32]
// ---------------------------------------------------------------------------
template<int CIN, int COP, int COUT>
__global__ __launch_bounds__(256) void pack_w_k(
    const float* __restrict__ src, _Float16* __restrict__ dst)
{
    const int bx = blockIdx.x;          // chunk*9 + k
    const int chunk = bx / 9, k = bx % 9;
    for (int i = threadIdx.x; i < COP * 32; i += 256) {
        const int co = i >> 5, cil = i & 31;
        float v = 0.f;
        if (co < COUT)
            v = src[((size_t)(co * CIN + chunk * 32 + cil)) * 9 + k];
        dst[(size_t)bx * COP * 32 + i] = (_Float16)v;
    }
}

// ---------------------------------------------------------------------------
// Prep: x fp32 [128][192][192] -> group-blocked NHWC fp16 xg[16][PH][PW][8],
// zero pad of 6 on all sides (buffer memset 0 first).
// ---------------------------------------------------------------------------
__global__ __launch_bounds__(192) void xg_pack_k(
    const float* __restrict__ x, _Float16* __restrict__ xg)
{
    const int y  = blockIdx.x;   // 0..191
    const int dg = blockIdx.y;   // 0..15
    const int xc = threadIdx.x;  // 0..191
    h8 v;
#pragma unroll
    for (int chl = 0; chl < 8; chl++)
        v[chl] = (_Float16)x[(size_t)(dg * 8 + chl) * NPIX + y * IMG_W + xc];
    *(h8*)&xg[(((size_t)dg * PH + y + 6) * PW + xc + 6) * 8] = v;
}

// ---------------------------------------------------------------------------
// Prep: deform weight fp32 [64][128][3][3] -> fp16 wdg[16 dg][64 co][96],
// ks = k*8 + chl (pad 72..95 zero).
// ---------------------------------------------------------------------------
__global__ __launch_bounds__(256) void wdg_pack_k(
    const float* __restrict__ w, _Float16* __restrict__ wdg)
{
    const int i = blockIdx.x * 256 + threadIdx.x;
    if (i >= 16 * 64 * 96) return;
    const int ks = i % 96;
    const int rest = i / 96;
    const int co = rest % 64;
    const int dg = rest / 64;
    const int k = ks >> 3, chl = ks & 7;
    float v = 0.f;
    if (ks < 72)
        v = w[((size_t)co * 128 + dg * 8 + chl) * 9 + k];
    wdg[i] = (_Float16)v;
}

// ---------------------------------------------------------------------------
// MFMA conv3x3 (unchanged from R2 — verified).
// ---------------------------------------------------------------------------
template<int CHUNKS, int ACT, int COP>
__global__ __launch_bounds__(256) void conv_mfma_k(
    const _Float16* __restrict__ in_pad,   // [CIN][PPIX]
    const _Float16* __restrict__ wpk,      // [CHUNKS][9][COP][32]
    const float* __restrict__ bias,
    _Float16* __restrict__ out)
{
    __shared__ _Float16 in_lds[324 * 32];  // [pix 18x18][ci 32]
    __shared__ _Float16 w_lds[9 * 64 * 32];// [k][co 64][ci 32]

    const int t    = threadIdx.x;
    const int lane = t & 63;
    const int wv   = __builtin_amdgcn_readfirstlane(t >> 6);
    const int col  = lane & 15;
    const int quad = lane >> 4;
    const int bx   = blockIdx.x;
    const int tx0  = (bx % 12) * 16;
    const int ty0  = (bx / 12) * 16;
    const int cobase = blockIdx.y * 64;

    f32x4 acc[4][4];
#pragma unroll
    for (int m = 0; m < 4; m++)
#pragma unroll
        for (int s = 0; s < 4; s++) {
            f32x4 z = {0.f, 0.f, 0.f, 0.f};
            acc[m][s] = z;
        }

    for (int c = 0; c < CHUNKS; c++) {
        __syncthreads();
        for (int p = t; p < 288; p += 256) {
            const int row = p >> 4;
            const int ci2 = p & 15;
            const size_t gbase = ((size_t)(c * 32 + 2 * ci2)) * PPIX
                               + (size_t)(ty0 + row) * PADW + tx0;
            const unsigned int* gA = (const unsigned int*)(in_pad + gbase);
            const unsigned int* gB = (const unsigned int*)(in_pad + gbase + PPIX);
            unsigned int* dst = (unsigned int*)in_lds;
#pragma unroll
            for (int j = 0; j < 9; j++) {
                const unsigned int a = gA[j], b = gB[j];
                const int pix = row * 18 + 2 * j;
                dst[pix * 16 + ci2]       = (a & 0xffffu) | (b << 16);
                dst[(pix + 1) * 16 + ci2] = (a >> 16) | (b & 0xffff0000u);
            }
        }
        for (int p = t; p < 576; p += 256) {
            const int k = p >> 6, co = p & 63;
            const uint4* s4 = (const uint4*)(wpk
                + (((size_t)c * 9 + k) * COP + cobase + co) * 32);
            uint4* dl = (uint4*)&w_lds[(k * 64 + co) * 32];
            dl[0] = s4[0]; dl[1] = s4[1]; dl[2] = s4[2]; dl[3] = s4[3];
        }
        __syncthreads();

#pragma unroll
        for (int k = 0; k < 9; k++) {
            const int ky = k / 3, kx = k % 3;
            h8 af[4], bf[4];
#pragma unroll
            for (int m = 0; m < 4; m++)
                af[m] = *(const h8*)&w_lds[(k * 64 + m * 16 + col) * 32 + quad * 8];
#pragma unroll
            for (int s = 0; s < 4; s++)
                bf[s] = *(const h8*)&in_lds[((4 * wv + s + ky) * 18 + col + kx) * 32 + quad * 8];
#pragma unroll
            for (int m = 0; m < 4; m++)
#pragma unroll
                for (int s = 0; s < 4; s++)
                    acc[m][s] = __builtin_amdgcn_mfma_f32_16x16x32_f16(
                        af[m], bf[s], acc[m][s], 0, 0, 0);
        }
    }

#pragma unroll
    for (int m = 0; m < 4; m++) {
#pragma unroll
        for (int s = 0; s < 4; s++) {
            const int gy = ty0 + 4 * wv + s;
            const int gx = tx0 + col;
#pragma unroll
            for (int r = 0; r < 4; r++) {
                const int co = cobase + m * 16 + quad * 4 + r;
                float v = acc[m][s][r];
                if (ACT == 1) {
                    v += bias[co];
                    v = (v >= 0.f) ? v : 0.1f * v;
                    out[(size_t)co * PPIX + (gy + 1) * PADW + (gx + 1)] = (_Float16)v;
                } else {
                    if (co < 432) {
                        v += bias[co];
                        if (co < 288) v = 5.f * tanhf(v);
                        else          v = 1.f / (1.f + __expf(-v));
                        out[(size_t)co * NPIX + gy * IMG_W + gx] = (_Float16)v;
                    }
                }
            }
        }
    }
}

// ---------------------------------------------------------------------------
// Deformable conv, MFMA version. Tile = 32x1 px, 64 co; 1152 blocks x 256.
// ---------------------------------------------------------------------------
__global__ __launch_bounds__(256) void deform_mfma_k(
    const _Float16* __restrict__ xg,   // [16][PH][PW][8]
    const _Float16* __restrict__ od,   // [432][NPIX] activated
    const _Float16* __restrict__ wdg,  // [16][64][96]
    const float* __restrict__ bias,
    float* __restrict__ out)
{
    __shared__ __align__(16) _Float16 val4[4][32][104];

    const int t    = threadIdx.x;
    const int lane = t & 63;
    const int wv   = __builtin_amdgcn_readfirstlane(t >> 6);
    const int col  = lane & 15;
    const int quad = lane >> 4;
    const int bx   = blockIdx.x;        // 192 rows * 6 segments
    const int gy   = bx / 6;
    const int gx0  = (bx % 6) * 32;
    const int pixrow = gy * IMG_W + gx0;

    for (int i = t; i < 4 * 32 * 4; i += 256) {
        const int dgl = i >> 7;
        const int r   = i & 127;
        const int px  = r >> 2;
        const int j   = r & 3;
        h8 z = {0, 0, 0, 0, 0, 0, 0, 0};
        *(h8*)&val4[dgl][px][72 + 8 * j] = z;
    }

    f32x4 acc[2];
    {
        f32x4 z = {0.f, 0.f, 0.f, 0.f};
        acc[0] = z; acc[1] = z;
    }

    for (int dq = 0; dq < 4; dq++) {
        __syncthreads();
        for (int idx = t; idx < 1152; idx += 256) {
            const int pxl  = idx & 31;
            const int rest = idx >> 5;      // 0..35
            const int k    = rest % 9;
            const int dgl  = rest / 9;
            const int dg   = dq * 4 + dgl;
            const int kc   = dg * 9 + k;
            const int pix  = pixrow + pxl;
            const float oy = (float)od[(size_t)(2 * kc) * NPIX + pix];
            const float ox = (float)od[(size_t)(2 * kc + 1) * NPIX + pix];
            const float m  = (float)od[(size_t)(288 + kc) * NPIX + pix];
            const float py  = (float)(gy - 1 + k / 3) + oy;
            const float pxx = (float)(gx0 + pxl - 1 + k % 3) + ox;
            const float y0 = floorf(py), x0 = floorf(pxx);
            const float fy = py - y0, fx = pxx - x0;
            const int iy = (int)y0 + 6, ix = (int)x0 + 6;
            const _Float16* p = xg + (((size_t)dg * PH + iy) * PW + ix) * 8;
            const h8 c00 = *(const h8*)p;
            const h8 c01 = *(const h8*)(p + 8);
            const h8 c10 = *(const h8*)(p + PW * 8);
            const h8 c11 = *(const h8*)(p + PW * 8 + 8);
            const float ey = 1.f - fy, ex = 1.f - fx;
            const _Float16 s00 = (_Float16)(ey * ex * m);
            const _Float16 s01 = (_Float16)(ey * fx * m);
            const _Float16 s10 = (_Float16)(fy * ex * m);
            const _Float16 s11 = (_Float16)(fy * fx * m);
            const h8 v = c00 * s00 + c01 * s01 + c10 * s10 + c11 * s11;
            *(h8*)&val4[dgl][pxl][k * 8] = v;
        }
        __syncthreads();

#pragma unroll
        for (int dgl = 0; dgl < 4; dgl++) {
            const int dg = dq * 4 + dgl;
            const _Float16* wbase = wdg + ((size_t)dg * 64 + wv * 16 + col) * 96;
#pragma unroll
            for (int ks = 0; ks < 3; ks++) {
                const h8 a  = *(const h8*)(wbase + ks * 32 + quad * 8);
                const h8 b0 = *(const h8*)&val4[dgl][col][ks * 32 + quad * 8];
                const h8 b1 = *(const h8*)&val4[dgl][16 + col][ks * 32 + quad * 8];
                acc[0] = __builtin_amdgcn_mfma_f32_16x16x32_f16(a, b0, acc[0], 0, 0, 0);
                acc[1] = __builtin_amdgcn_mfma_f32_16x16x32_f16(a, b1, acc[1], 0, 0, 0);
            }
        }
    }

    const int co = wv * 16 + quad * 4;
#pragma unroll
    for (int n = 0; n < 2; n++) {
        const int gx = gx0 + n * 16 + col;
#pragma unroll
        for (int r = 0; r < 4; r++)
            out[(size_t)(co + r) * NPIX + gy * IMG_W + gx] = acc[n][r] + bias[co + r];
    }
}

// ---------------------------------------------------------------------------
// Launch
// ---------------------------------------------------------------------------
extern "C" void kernel_launch(void* const* d_in, const int* in_sizes, int n_in,
                              void* d_out, int out_size, void* d_ws, size_t ws_size,
                              hipStream_t stream) {
    (void)in_sizes; (void)n_in; (void)out_size; (void)ws_size;

    const float* x      = (const float*)d_in[0];
    const float* cond   = (const float*)d_in[1];
    const float* weight = (const float*)d_in[2];
    const float* bias   = (const float*)d_in[3];
    const float* w1     = (const float*)d_in[4];
    const float* b1     = (const float*)d_in[5];
    const float* w2     = (const float*)d_in[6];
    const float* b2     = (const float*)d_in[7];
    const float* w3     = (const float*)d_in[8];
    const float* b3     = (const float*)d_in[9];
    const float* w4     = (const float*)d_in[10];
    const float* b4     = (const float*)d_in[11];
    float* out = (float*)d_out;

    char* ws = (char*)d_ws;
    size_t off = 0;
    auto take = [&](size_t bytes) -> char* {
        char* p = ws + off;
        off = (off + bytes + 255) & ~(size_t)255;
        return p;
    };
    _Float16* pad_cond = (_Float16*)take((size_t)192 * PPIX * 2);
    _Float16* pb1      = (_Float16*)take((size_t)3 * 64 * PPIX * 2);
    _Float16* pb2 = pb1 + (size_t)64 * PPIX;
    _Float16* pb3 = pb2 + (size_t)64 * PPIX;
    _Float16* od  = (_Float16*)take((size_t)432 * NPIX * 2);
    _Float16* wp1 = (_Float16*)take((size_t)54 * 64 * 32 * 2);
    _Float16* wp2 = (_Float16*)take((size_t)18 * 64 * 32 * 2);
    _Float16* wp3 = (_Float16*)take((size_t)18 * 64 * 32 * 2);
    _Float16* wp4 = (_Float16*)take((size_t)18 * 448 * 32 * 2);
    _Float16* xg  = (_Float16*)take((size_t)16 * PH * PW * 8 * 2);
    _Float16* wdg = (_Float16*)take((size_t)16 * 64 * 96 * 2);

    hipMemsetAsync(pb1, 0, (size_t)3 * 64 * PPIX * 2, stream);
    hipMemsetAsync(xg,  0, (size_t)16 * PH * PW * 8 * 2, stream);

    hipLaunchKernelGGL(pad_to_half_k, dim3(PADW, 192), dim3(256), 0, stream, cond, pad_cond);
    hipLaunchKernelGGL((pack_w_k<192, 64, 64>),  dim3(54), dim3(256), 0, stream, w1, wp1);
    hipLaunchKernelGGL((pack_w_k<64, 64, 64>),   dim3(18), dim3(256), 0, stream, w2, wp2);
    hipLaunchKernelGGL((pack_w_k<64, 64, 64>),   dim3(18), dim3(256), 0, stream, w3, wp3);
    hipLaunchKernelGGL((pack_w_k<64, 448, 432>), dim3(18), dim3(256), 0, stream, w4, wp4);
    hipLaunchKernelGGL(xg_pack_k,  dim3(192, 16), dim3(192), 0, stream, x, xg);
    hipLaunchKernelGGL(wdg_pack_k, dim3((16 * 64 * 96 + 255) / 256), dim3(256), 0, stream, weight, wdg);

    hipLaunchKernelGGL((conv_mfma_k<6, 1, 64>),  dim3(144, 1), dim3(256), 0, stream, pad_cond, wp1, b1, pb1);
    hipLaunchKernelGGL((conv_mfma_k<2, 1, 64>),  dim3(144, 1), dim3(256), 0, stream, pb1, wp2, b2, pb2);
    hipLaunchKernelGGL((conv_mfma_k<2, 1, 64>),  dim3(144, 1), dim3(256), 0, stream, pb2, wp3, b3, pb3);
    hipLaunchKernelGGL((conv_mfma_k<2, 2, 448>), dim3(144, 7), dim3(256), 0, stream, pb3, wp4, b4, od);
    hipLaunchKernelGGL(deform_mfma_k, dim3(1152), dim3(256), 0, stream, xg, od, wdg, bias, out);
}